// Round 11
// baseline (1420.962 us; speedup 1.0000x reference)
//
#include <hip/hip_runtime.h>
#include <stdint.h>

#define B_ 4
#define N_TOK 1024
#define DM 256
#define DEPTH 12
#define DSTATE 16
#define DIN 512
#define LVIS 768
#define MROWS (B_ * LVIS)  // 3072
#define NCHUNK 128
#define CLEN 6             // 768 / 128
#define EPS_F 1e-5f

typedef __attribute__((ext_vector_type(8))) short s8v;   // 8 bf16 (4 VGPRs)
typedef __attribute__((ext_vector_type(4))) float f4v;   // 4 f32 acc

// ---------- helpers ----------
__device__ __forceinline__ float bs2f(uint32_t u) {
  uint32_t x = (u & 0xffffu) << 16;
  float f; __builtin_memcpy(&f, &x, 4); return f;
}
__device__ __forceinline__ uint16_t f2b(float f) {
  uint32_t u; __builtin_memcpy(&u, &f, 4);
  return (uint16_t)((u + 0x7fffu + ((u >> 16) & 1u)) >> 16);
}
__device__ __forceinline__ float silu_f(float x) { return x / (1.f + __expf(-x)); }
__device__ __forceinline__ float softplus_f(float x) {
  return fmaxf(x, 0.f) + log1pf(__expf(-fabsf(x)));
}
__device__ __forceinline__ float block_sum256(float v, volatile float* scr) {
  int t = threadIdx.x, lane = t & 63, wid = t >> 6;
#pragma unroll
  for (int o = 32; o > 0; o >>= 1) v += __shfl_down(v, o);
  __syncthreads();
  if (lane == 0) scr[wid] = v;
  __syncthreads();
  return scr[0] + scr[1] + scr[2] + scr[3];
}

// ---------- dtype detection ----------
__global__ void detect_kernel(const void* mask, const uint32_t* nf, int* flags) {
  __shared__ int cnt[3];
  int t = threadIdx.x;
  if (t < 3) cnt[t] = 0;
  __syncthreads();
  const uint32_t* pi = (const uint32_t*)mask;
  const uint16_t* ph = (const uint16_t*)mask;
  const uint8_t*  pb = (const uint8_t*)mask;
  int c32 = 0, cbf = 0, c8 = 0;
  for (int i = t; i < 1024; i += 256) {
    c32 += (pi[i] != 0u);
    cbf += (ph[i] != 0);
    c8  += (pb[i] != 0);
  }
  atomicAdd(&cnt[0], c32);
  atomicAdd(&cnt[1], cbf);
  atomicAdd(&cnt[2], c8);
  __syncthreads();
  if (t == 0) {
    int f;
    if (cnt[0] == 256) f = 0;
    else if (cnt[1] == 256) f = 2;
    else f = 1;
    flags[0] = f;
    flags[1] = (nf[0] == 0x3F800000u) ? 0 : 1;
  }
}

// ---------- single batched conversion of all 13 param arrays ----------
struct CvtArgs {
  const void* src[13];
  void*       dst[13];
  int         n[13];
  int         isb16[13];
};
__global__ __launch_bounds__(256) void cvt_all_kernel(CvtArgs a, int total,
                                                      const int* __restrict__ flags) {
  int e = blockIdx.x * 256 + threadIdx.x;
  if (e >= total) return;
  int i = 0;
  while (e >= a.n[i]) { e -= a.n[i]; ++i; }
  int srcb16 = flags[1];
  if (a.isb16[i]) {
    uint16_t v = srcb16 ? ((const uint16_t*)a.src[i])[e]
                        : f2b(((const float*)a.src[i])[e]);
    ((uint16_t*)a.dst[i])[e] = v;
  } else {
    float v = srcb16 ? bs2f(((const uint16_t*)a.src[i])[e])
                     : ((const float*)a.src[i])[e];
    ((float*)a.dst[i])[e] = v;
  }
}

// ---------- visible-index compaction (stable) ----------
__global__ __launch_bounds__(1024) void order_kernel(const void* mask,
                                                     const int* __restrict__ flags,
                                                     int* __restrict__ order) {
  int b = blockIdx.x, i = threadIdx.x;
  int f = flags[0];
  int mv;
  if (f == 0)      mv = (((const uint32_t*)mask)[b * N_TOK + i] != 0u);
  else if (f == 1) mv = (((const uint8_t*)mask)[b * N_TOK + i] != 0);
  else             mv = (((const uint16_t*)mask)[b * N_TOK + i] != 0);
  int vis = !mv;
  unsigned long long mb = __ballot(vis);
  int lane = i & 63, wid = i >> 6;
  int wpre = __popcll(mb & ((1ull << lane) - 1ull));
  __shared__ int wsum[16];
  __shared__ int woff[16];
  if (lane == 0) wsum[wid] = __popcll(mb);
  __syncthreads();
  if (i == 0) { int a = 0; for (int w = 0; w < 16; ++w) { woff[w] = a; a += wsum[w]; } }
  __syncthreads();
  if (vis) {
    int pos = woff[wid] + wpre;
    if (pos < LVIS) order[b * LVIS + pos] = i;
  }
}

// ---------- gather tokens -> residual (= r_1); rms -> rmsb16 ----------
__global__ __launch_bounds__(256) void gather_rms_kernel(const void* __restrict__ tokens,
                                                         const int* __restrict__ order,
                                                         const int* __restrict__ flags,
                                                         const float* __restrict__ nw,
                                                         float* __restrict__ residual,
                                                         uint16_t* __restrict__ rmsb16) {
  __shared__ float scr[4];
  int row = blockIdx.x;
  int b = row / LVIS;
  int d = threadIdx.x;
  int idx = order[row];
  size_t src = ((size_t)(b * N_TOK + idx)) * DM + d;
  float v = flags[1] ? bs2f(((const uint16_t*)tokens)[src]) : ((const float*)tokens)[src];
  size_t i = (size_t)row * DM + d;
  residual[i] = v;
  float ss = block_sum256(v * v, scr);
  rmsb16[i] = f2b(v * rsqrtf(ss / DM + EPS_F) * nw[d]);
}

// ---------- pipelined LDS-staged MFMA bf16 GEMM (in_proj), bf16 out ----------
#define GS 36
__global__ __launch_bounds__(256) void mfma_gemm_kernel(const uint16_t* __restrict__ A,
                                                        const uint16_t* __restrict__ W,
                                                        uint16_t* __restrict__ C,
                                                        int N, int K) {
  __shared__ uint16_t As[64 * GS];
  __shared__ uint16_t Ws[64 * GS];
  const int t = threadIdx.x;
  const int wv = t >> 6, lane = t & 63;
  const int lm = lane & 15, lq = lane >> 4;
  const int m0 = blockIdx.y * 64, n0 = blockIdx.x * 64;
  const int r = t >> 2, seg = t & 3;
  const uint16_t* ag = A + (size_t)(m0 + r) * K + seg * 8;
  const uint16_t* wg = W + (size_t)(n0 + r) * K + seg * 8;
  uint16_t* asl = As + r * GS + seg * 8;
  uint16_t* wsl = Ws + r * GS + seg * 8;
  const uint16_t* afr = As + (wv * 16 + lm) * GS + lq * 8;
  const uint16_t* wfr = Ws + lm * GS + lq * 8;
  f4v acc[4];
#pragma unroll
  for (int j = 0; j < 4; ++j) acc[j] = (f4v){0.f, 0.f, 0.f, 0.f};
  uint4 av = *(const uint4*)(ag);
  uint4 wvv = *(const uint4*)(wg);
  for (int k0 = 0; k0 < K; k0 += 32) {
    __syncthreads();
    *(uint4*)asl = av;
    *(uint4*)wsl = wvv;
    __syncthreads();
    if (k0 + 32 < K) {  // prefetch next K-step; overlaps with MFMAs below
      av = *(const uint4*)(ag + k0 + 32);
      wvv = *(const uint4*)(wg + k0 + 32);
    }
    s8v a = *(const s8v*)afr;
#pragma unroll
    for (int j = 0; j < 4; ++j) {
      s8v b = *(const s8v*)(wfr + j * 16 * GS);
      acc[j] = __builtin_amdgcn_mfma_f32_16x16x32_bf16(a, b, acc[j], 0, 0, 0);
    }
  }
#pragma unroll
  for (int j = 0; j < 4; ++j) {
    int col = n0 + j * 16 + lm;
#pragma unroll
    for (int rr = 0; rr < 4; ++rr) {
      int row = m0 + wv * 16 + lq * 4 + rr;
      C[(size_t)row * N + col] = f2b(acc[j][rr]);
    }
  }
}

// carry-state layout: idx(b,c,s,d) = ((b*NCHUNK + c)*16 + s)*DIN + d  (d innermost)
__device__ __forceinline__ size_t cidx(int b, int c, int s, int d) {
  return (((size_t)(b * NCHUNK + c) * 16 + s)) * DIN + d;
}

// ---------- scan1: fused conv+silu+x_proj GEMM (split-K-8 over 8 waves) +
//            inline conv+dt + chunk-local scan. block = one (b,c), 512 thr ----------
__global__ __launch_bounds__(512) void scan1_kernel(
    const uint16_t* __restrict__ xz16, const uint16_t* __restrict__ xw,
    const float* __restrict__ cw, const float* __restrict__ cb,
    const float* __restrict__ dtw, const float* __restrict__ dtb,
    const float* __restrict__ Alog,
    float* __restrict__ hend, float* __restrict__ pend,
    float* __restrict__ xdbl_out) {
  __shared__ float red[8][768];
  __shared__ float xds[CLEN * 48];
  const int t = threadIdx.x;
  const int c = blockIdx.x & (NCHUNK - 1);
  const int b = blockIdx.x >> 7;
  const int rowbase = b * LVIS + c * CLEN;
  // ---- GEMM phase: conv(4)+silu A-fragment, 16x48 tile, wave = K-slice of 64
  {
    const int wv = t >> 6, lane = t & 63;
    const int lm = lane & 15, lq = lane >> 4;
    int grow = rowbase + lm;
    if (grow > MROWS - 1) grow = MROWS - 1;  // pad-row clamp (b=3,c=127)
    const int l = grow % LVIS;
    const uint16_t* xrow = xz16 + (size_t)grow * 1024;
    const bool t3 = l >= 3, t2 = l >= 2, t1 = l >= 1;
    const s8v zv = {0, 0, 0, 0, 0, 0, 0, 0};
    f4v acc[3];
#pragma unroll
    for (int j = 0; j < 3; ++j) acc[j] = (f4v){0.f, 0.f, 0.f, 0.f};
#pragma unroll
    for (int ki = 0; ki < 2; ++ki) {
      int kk = wv * 64 + ki * 32 + lq * 8;
      s8v x3 = t3 ? *(const s8v*)(xrow - 3 * 1024 + kk) : zv;
      s8v x2 = t2 ? *(const s8v*)(xrow - 2 * 1024 + kk) : zv;
      s8v x1 = t1 ? *(const s8v*)(xrow - 1 * 1024 + kk) : zv;
      s8v x0 = *(const s8v*)(xrow + kk);
      short av[8];
#pragma unroll
      for (int j = 0; j < 8; ++j) {
        int ch = kk + j;
        float4 w = *(const float4*)(cw + ch * 4);
        float a = cb[ch] + bs2f((uint16_t)x3[j]) * w.x + bs2f((uint16_t)x2[j]) * w.y +
                  bs2f((uint16_t)x1[j]) * w.z + bs2f((uint16_t)x0[j]) * w.w;
        av[j] = (short)f2b(silu_f(a));
      }
      s8v a8 = {av[0], av[1], av[2], av[3], av[4], av[5], av[6], av[7]};
#pragma unroll
      for (int j = 0; j < 3; ++j) {
        s8v bb = *(const s8v*)(xw + (size_t)(j * 16 + lm) * DIN + kk);
        acc[j] = __builtin_amdgcn_mfma_f32_16x16x32_bf16(a8, bb, acc[j], 0, 0, 0);
      }
    }
#pragma unroll
    for (int j = 0; j < 3; ++j)
#pragma unroll
      for (int rr = 0; rr < 4; ++rr)
        red[wv][(lq * 4 + rr) * 48 + j * 16 + lm] = acc[j][rr];
  }
  __syncthreads();
  for (int e = t; e < CLEN * 48; e += 512) {
    float v = red[0][e] + red[1][e] + red[2][e] + red[3][e] +
              red[4][e] + red[5][e] + red[6][e] + red[7][e];
    xds[e] = v;
    xdbl_out[(size_t)(rowbase + e / 48) * 48 + (e % 48)] = v;
  }
  // ---- scan phase: d = t (full 512 range) ----
  const int d = t;
  float A[16], dw[16];
  {
    const float4* ap = (const float4*)(Alog + (size_t)d * 16);
    const float4* wp = (const float4*)(dtw + (size_t)d * 16);
#pragma unroll
    for (int q = 0; q < 4; ++q) {
      float4 a4 = ap[q], w4 = wp[q];
      A[4 * q + 0] = -__expf(a4.x); A[4 * q + 1] = -__expf(a4.y);
      A[4 * q + 2] = -__expf(a4.z); A[4 * q + 3] = -__expf(a4.w);
      dw[4 * q + 0] = w4.x; dw[4 * q + 1] = w4.y;
      dw[4 * q + 2] = w4.z; dw[4 * q + 3] = w4.w;
    }
  }
  float dtbv = dtb[d], cbv = cb[d];
  float4 cwv = *(const float4*)(cw + d * 4);
  float w3 = 0.f, w2 = 0.f, w1 = 0.f;
  if (c > 0) {
    w3 = bs2f(xz16[(size_t)(rowbase - 3) * 1024 + d]);
    w2 = bs2f(xz16[(size_t)(rowbase - 2) * 1024 + d]);
    w1 = bs2f(xz16[(size_t)(rowbase - 1) * 1024 + d]);
  }
  __syncthreads();
  float h[16], p[16];
#pragma unroll
  for (int s = 0; s < 16; ++s) { h[s] = 0.f; p[s] = 1.f; }
  for (int l = 0; l < CLEN; ++l) {
    int row = rowbase + l;
    float xn = bs2f(xz16[(size_t)row * 1024 + d]);
    float xv = silu_f(cbv + w3 * cwv.x + w2 * cwv.y + w1 * cwv.z + xn * cwv.w);
    w3 = w2; w2 = w1; w1 = xn;
    const float* xd = xds + l * 48;
    float dtraw = dtbv;
#pragma unroll
    for (int q = 0; q < 16; ++q) dtraw += xd[q] * dw[q];
    float dtv = softplus_f(dtraw);
    float dtx = dtv * xv;
#pragma unroll
    for (int s = 0; s < 16; ++s) {
      float dA = __expf(dtv * A[s]);
      h[s] = dA * h[s] + dtx * xd[16 + s];
      p[s] *= dA;
    }
  }
#pragma unroll
  for (int s = 0; s < 16; ++s) {
    hend[cidx(b, c, s, d)] = h[s];
    pend[cidx(b, c, s, d)] = p[s];
  }
}

// ---------- scan2: serial carry across chunks (coalesced, d innermost) ----------
__global__ __launch_bounds__(256) void scan2_kernel(const float* __restrict__ hend,
                                                    const float* __restrict__ pend,
                                                    float* __restrict__ hin) {
  int g = blockIdx.x * 256 + threadIdx.x;  // B_*16*DIN = 32768
  int d = g & (DIN - 1);
  int s = (g >> 9) & 15;
  int b = g >> 13;
  float h = 0.f;
  for (int c = 0; c < NCHUNK; ++c) {
    size_t idx = cidx(b, c, s, d);
    hin[idx] = h;
    h = pend[idx] * h + hend[idx];
  }
}

// ---------- scan3: rescan with carry; LDS-staged xdbl; gate; emit bf16 ----------
// block = one (b,c), 512 threads.
__global__ __launch_bounds__(512) void scan3_kernel(
    const uint16_t* __restrict__ xz16, const float* __restrict__ xdbl,
    const float* __restrict__ dtw, const float* __restrict__ dtb,
    const float* __restrict__ cw, const float* __restrict__ cb,
    const float* __restrict__ Alog, const float* __restrict__ Dskip,
    const float* __restrict__ hin, uint16_t* __restrict__ ymul16) {
  __shared__ float xds[CLEN * 48];
  const int t = threadIdx.x;
  const int c = blockIdx.x & (NCHUNK - 1);
  const int b = blockIdx.x >> 7;
  const int rowbase = b * LVIS + c * CLEN;
  for (int e = t; e < CLEN * 48; e += 512)
    xds[e] = xdbl[(size_t)(rowbase + e / 48) * 48 + (e % 48)];
  const int d = t;
  float A[16], dw[16];
  {
    const float4* ap = (const float4*)(Alog + (size_t)d * 16);
    const float4* wp = (const float4*)(dtw + (size_t)d * 16);
#pragma unroll
    for (int q = 0; q < 4; ++q) {
      float4 a4 = ap[q], w4 = wp[q];
      A[4 * q + 0] = -__expf(a4.x); A[4 * q + 1] = -__expf(a4.y);
      A[4 * q + 2] = -__expf(a4.z); A[4 * q + 3] = -__expf(a4.w);
      dw[4 * q + 0] = w4.x; dw[4 * q + 1] = w4.y;
      dw[4 * q + 2] = w4.z; dw[4 * q + 3] = w4.w;
    }
  }
  float h[16];
#pragma unroll
  for (int s = 0; s < 16; ++s) h[s] = hin[cidx(b, c, s, d)];
  float dtbv = dtb[d], cbv = cb[d], Dv = Dskip[d];
  float4 cwv = *(const float4*)(cw + d * 4);
  float w3 = 0.f, w2 = 0.f, w1 = 0.f;
  if (c > 0) {
    w3 = bs2f(xz16[(size_t)(rowbase - 3) * 1024 + d]);
    w2 = bs2f(xz16[(size_t)(rowbase - 2) * 1024 + d]);
    w1 = bs2f(xz16[(size_t)(rowbase - 1) * 1024 + d]);
  }
  __syncthreads();
  for (int l = 0; l < CLEN; ++l) {
    int row = rowbase + l;
    float xn = bs2f(xz16[(size_t)row * 1024 + d]);
    float xv = silu_f(cbv + w3 * cwv.x + w2 * cwv.y + w1 * cwv.z + xn * cwv.w);
    w3 = w2; w2 = w1; w1 = xn;
    const float* xd = xds + l * 48;
    float dtraw = dtbv;
#pragma unroll
    for (int q = 0; q < 16; ++q) dtraw += xd[q] * dw[q];
    float dtv = softplus_f(dtraw);
    float dtx = dtv * xv;
    float y = 0.f;
#pragma unroll
    for (int s = 0; s < 16; ++s) {
      float dA = __expf(dtv * A[s]);
      h[s] = dA * h[s] + dtx * xd[16 + s];
      y += h[s] * xd[32 + s];
    }
    float zv = bs2f(xz16[(size_t)row * 1024 + 512 + d]);
    ymul16[(size_t)row * DIN + d] = f2b((y + Dv * xv) * silu_f(zv));
  }
}

// ---------- out_proj + residual update + rms for next layer (pipelined) ----------
__global__ __launch_bounds__(256) void outproj_rms_kernel(
    const uint16_t* __restrict__ ymul16, const uint16_t* __restrict__ W,
    const float* __restrict__ nw, float* __restrict__ residual,
    uint16_t* __restrict__ rmsb16) {
  __shared__ uint16_t As[64 * GS];
  __shared__ uint16_t Ws[256 * GS];
  const int t = threadIdx.x;
  const int wv = t >> 6, lane = t & 63;
  const int lm = lane & 15, lq = lane >> 4;
  const int m0 = blockIdx.x * 64;
  const int r4 = t >> 2, seg = t & 3;
  f4v acc[16];
#pragma unroll
  for (int j = 0; j < 16; ++j) acc[j] = (f4v){0.f, 0.f, 0.f, 0.f};
  const uint16_t* afr = As + (wv * 16 + lm) * GS + lq * 8;
  uint4 pa = *(const uint4*)(ymul16 + (size_t)(m0 + r4) * DIN + seg * 8);
  uint4 pw[4];
#pragma unroll
  for (int rr = 0; rr < 4; ++rr)
    pw[rr] = *(const uint4*)(W + (size_t)(rr * 64 + r4) * DIN + seg * 8);
  for (int k0 = 0; k0 < DIN; k0 += 32) {
    __syncthreads();
    *(uint4*)(As + r4 * GS + seg * 8) = pa;
#pragma unroll
    for (int rr = 0; rr < 4; ++rr)
      *(uint4*)(Ws + (rr * 64 + r4) * GS + seg * 8) = pw[rr];
    __syncthreads();
    if (k0 + 32 < DIN) {  // prefetch next step
      pa = *(const uint4*)(ymul16 + (size_t)(m0 + r4) * DIN + k0 + 32 + seg * 8);
#pragma unroll
      for (int rr = 0; rr < 4; ++rr)
        pw[rr] = *(const uint4*)(W + (size_t)(rr * 64 + r4) * DIN + k0 + 32 + seg * 8);
    }
    s8v a = *(const s8v*)afr;
#pragma unroll
    for (int j = 0; j < 16; ++j) {
      s8v b = *(const s8v*)(Ws + (j * 16 + lm) * GS + lq * 8);
      acc[j] = __builtin_amdgcn_mfma_f32_16x16x32_bf16(a, b, acc[j], 0, 0, 0);
    }
  }
  float sum[4] = {0.f, 0.f, 0.f, 0.f};
#pragma unroll
  for (int rr = 0; rr < 4; ++rr) {
    int row = m0 + wv * 16 + lq * 4 + rr;
#pragma unroll
    for (int j = 0; j < 16; ++j) {
      int col = j * 16 + lm;
      float v = acc[j][rr] + residual[(size_t)row * DM + col];
      acc[j][rr] = v;
      sum[rr] += v * v;
    }
  }
#pragma unroll
  for (int rr = 0; rr < 4; ++rr) {
#pragma unroll
    for (int o = 1; o < 16; o <<= 1) sum[rr] += __shfl_xor(sum[rr], o);
    sum[rr] = rsqrtf(sum[rr] / DM + EPS_F);
  }
#pragma unroll
  for (int rr = 0; rr < 4; ++rr) {
    int row = m0 + wv * 16 + lq * 4 + rr;
#pragma unroll
    for (int j = 0; j < 16; ++j) {
      int col = j * 16 + lm;
      float v = acc[j][rr];
      residual[(size_t)row * DM + col] = v;
      rmsb16[(size_t)row * DM + col] = f2b(v * sum[rr] * nw[col]);
    }
  }
}

// ---------- final: rmsnorm(residual) -> layernorm -> out (flag-typed) ----------
__global__ __launch_bounds__(256) void final_kernel(const float* __restrict__ residual,
                                                    const float* __restrict__ nfw,
                                                    const float* __restrict__ lnw,
                                                    const float* __restrict__ lnb,
                                                    const int* __restrict__ flags,
                                                    void* __restrict__ out) {
  __shared__ float scr[4];
  int row = blockIdx.x, d = threadIdx.x;
  size_t i = (size_t)row * DM + d;
  float v = residual[i];
  float ss = block_sum256(v * v, scr);
  float h = v * rsqrtf(ss / DM + EPS_F) * nfw[d];
  float mu = block_sum256(h, scr) / DM;
  float dv = h - mu;
  float var = block_sum256(dv * dv, scr) / DM;
  float o = dv * rsqrtf(var + EPS_F) * lnw[d] + lnb[d];
  int b = row / LVIS, l = row % LVIS;
  size_t oi = (l < LVIS - 1)
                ? ((size_t)(b * (LVIS - 1) + l) * DM + d)
                : ((size_t)B_ * (LVIS - 1) * DM + (size_t)b * DM + d);
  if (flags[1]) ((uint16_t*)out)[oi] = f2b(o);
  else          ((float*)out)[oi] = o;
}

// ---------- host ----------
extern "C" void kernel_launch(void* const* d_in, const int* in_sizes, int n_in,
                              void* d_out, int out_size, void* d_ws, size_t ws_size,
                              hipStream_t stream) {
  char* ws = (char*)d_ws;
  size_t off = 0;
  auto alloc = [&](size_t bytes) -> void* {
    void* p = ws + off;
    off += (bytes + 255) & ~(size_t)255;
    return p;
  };
  const int f32_idx[10] = {3, 4, 6, 7, 8, 9, 11, 12, 13, 14};
  const int b16_idx[3]  = {2, 5, 10};
  float*    f32c[15] = {nullptr};
  uint16_t* b16c[15] = {nullptr};
  for (int j = 0; j < 10; ++j) {
    int i = f32_idx[j];
    f32c[i] = (float*)alloc((size_t)in_sizes[i] * 4);
  }
  for (int j = 0; j < 3; ++j) {
    int i = b16_idx[j];
    b16c[i] = (uint16_t*)alloc((size_t)in_sizes[i] * 2);
  }
  float*    residual = (float*)alloc((size_t)MROWS * DM * 4);
  uint16_t* rmsb16   = (uint16_t*)alloc((size_t)MROWS * DM * 2);
  uint16_t* xz16     = (uint16_t*)alloc((size_t)MROWS * 1024 * 2);
  float*    xdbl     = (float*)alloc((size_t)MROWS * 48 * 4);
  uint16_t* ymul16   = (uint16_t*)alloc((size_t)MROWS * DIN * 2);
  float*    hend     = (float*)alloc((size_t)B_ * NCHUNK * DIN * 16 * 4);
  float*    pend     = (float*)alloc((size_t)B_ * NCHUNK * DIN * 16 * 4);
  float*    hin      = (float*)alloc((size_t)B_ * NCHUNK * DIN * 16 * 4);
  int*      order    = (int*)alloc((size_t)B_ * LVIS * 4);
  int*      flags    = (int*)alloc(256);

  detect_kernel<<<1, 256, 0, stream>>>(d_in[1], (const uint32_t*)d_in[12], flags);

  CvtArgs ca;
  int total = 0, slot = 0;
  for (int j = 0; j < 3; ++j) {
    int i = b16_idx[j];
    ca.src[slot] = d_in[i]; ca.dst[slot] = b16c[i];
    ca.n[slot] = in_sizes[i]; ca.isb16[slot] = 1;
    total += in_sizes[i]; ++slot;
  }
  for (int j = 0; j < 10; ++j) {
    int i = f32_idx[j];
    ca.src[slot] = d_in[i]; ca.dst[slot] = f32c[i];
    ca.n[slot] = in_sizes[i]; ca.isb16[slot] = 0;
    total += in_sizes[i]; ++slot;
  }
  cvt_all_kernel<<<(total + 255) / 256, 256, 0, stream>>>(ca, total, flags);

  const uint16_t* in_w   = b16c[2];
  const float*    conv_w = f32c[3];
  const float*    conv_b = f32c[4];
  const uint16_t* x_w    = b16c[5];
  const float*    dt_w   = f32c[6];
  const float*    dt_b   = f32c[7];
  const float*    A_log  = f32c[8];
  const float*    D_skip = f32c[9];
  const uint16_t* out_w  = b16c[10];
  const float*    norm_w = f32c[11];
  const float*    norm_f = f32c[12];
  const float*    ln_w   = f32c[13];
  const float*    ln_b   = f32c[14];

  order_kernel<<<B_, 1024, 0, stream>>>(d_in[1], flags, order);
  gather_rms_kernel<<<MROWS, 256, 0, stream>>>(d_in[0], order, flags, norm_w,
                                               residual, rmsb16);

  for (int L = 0; L < DEPTH; ++L) {
    mfma_gemm_kernel<<<dim3(16, 48), 256, 0, stream>>>(
        rmsb16, in_w + (size_t)L * 1024 * DM, xz16, 1024, DM);
    scan1_kernel<<<B_ * NCHUNK, 512, 0, stream>>>(
        xz16, x_w + (size_t)L * 48 * DIN,
        conv_w + (size_t)L * DIN * 4, conv_b + (size_t)L * DIN,
        dt_w + (size_t)L * DIN * 16, dt_b + (size_t)L * DIN,
        A_log + (size_t)L * DIN * 16, hend, pend, xdbl);
    scan2_kernel<<<(B_ * 16 * DIN) / 256, 256, 0, stream>>>(hend, pend, hin);
    scan3_kernel<<<B_ * NCHUNK, 512, 0, stream>>>(
        xz16, xdbl, dt_w + (size_t)L * DIN * 16, dt_b + (size_t)L * DIN,
        conv_w + (size_t)L * DIN * 4, conv_b + (size_t)L * DIN,
        A_log + (size_t)L * DIN * 16, D_skip + (size_t)L * DIN, hin, ymul16);
    int Lnext = (L + 1 < DEPTH) ? (L + 1) : L;
    outproj_rms_kernel<<<48, 256, 0, stream>>>(
        ymul16, out_w + (size_t)L * DM * DIN, norm_w + (size_t)Lnext * DM,
        residual, rmsb16);
  }

  final_kernel<<<MROWS, 256, 0, stream>>>(residual, norm_f, ln_w, ln_b,
                                          flags, d_out);
}

// Round 12
// 1097.311 us; speedup vs baseline: 1.2949x; 1.2949x over previous
//
#include <hip/hip_runtime.h>
#include <stdint.h>

#define B_ 4
#define N_TOK 1024
#define DM 256
#define DEPTH 12
#define DSTATE 16
#define DIN 512
#define LVIS 768
#define MROWS (B_ * LVIS)  // 3072
#define NCHUNK 64
#define CLEN 12            // 768 / 64
#define EPS_F 1e-5f
#define YS 520             // ymul LDS stride (shorts): 260 dwords -> bank shift 4/row

typedef __attribute__((ext_vector_type(8))) short s8v;   // 8 bf16 (4 VGPRs)
typedef __attribute__((ext_vector_type(4))) float f4v;   // 4 f32 acc

// ---------- helpers ----------
__device__ __forceinline__ float bs2f(uint32_t u) {
  uint32_t x = (u & 0xffffu) << 16;
  float f; __builtin_memcpy(&f, &x, 4); return f;
}
__device__ __forceinline__ uint16_t f2b(float f) {
  uint32_t u; __builtin_memcpy(&u, &f, 4);
  return (uint16_t)((u + 0x7fffu + ((u >> 16) & 1u)) >> 16);
}
__device__ __forceinline__ float silu_f(float x) { return x / (1.f + __expf(-x)); }
__device__ __forceinline__ float softplus_f(float x) {
  return fmaxf(x, 0.f) + log1pf(__expf(-fabsf(x)));
}
__device__ __forceinline__ float block_sum256(float v, volatile float* scr) {
  int t = threadIdx.x, lane = t & 63, wid = t >> 6;
#pragma unroll
  for (int o = 32; o > 0; o >>= 1) v += __shfl_down(v, o);
  __syncthreads();
  if (lane == 0) scr[wid] = v;
  __syncthreads();
  return scr[0] + scr[1] + scr[2] + scr[3];
}

// ---------- dtype detection ----------
__global__ void detect_kernel(const void* mask, const uint32_t* nf, int* flags) {
  __shared__ int cnt[3];
  int t = threadIdx.x;
  if (t < 3) cnt[t] = 0;
  __syncthreads();
  const uint32_t* pi = (const uint32_t*)mask;
  const uint16_t* ph = (const uint16_t*)mask;
  const uint8_t*  pb = (const uint8_t*)mask;
  int c32 = 0, cbf = 0, c8 = 0;
  for (int i = t; i < 1024; i += 256) {
    c32 += (pi[i] != 0u);
    cbf += (ph[i] != 0);
    c8  += (pb[i] != 0);
  }
  atomicAdd(&cnt[0], c32);
  atomicAdd(&cnt[1], cbf);
  atomicAdd(&cnt[2], c8);
  __syncthreads();
  if (t == 0) {
    int f;
    if (cnt[0] == 256) f = 0;
    else if (cnt[1] == 256) f = 2;
    else f = 1;
    flags[0] = f;
    flags[1] = (nf[0] == 0x3F800000u) ? 0 : 1;
  }
}

// ---------- single batched conversion of all 13 param arrays ----------
struct CvtArgs {
  const void* src[13];
  void*       dst[13];
  int         n[13];
  int         isb16[13];
};
__global__ __launch_bounds__(256) void cvt_all_kernel(CvtArgs a, int total,
                                                      const int* __restrict__ flags) {
  int e = blockIdx.x * 256 + threadIdx.x;
  if (e >= total) return;
  int i = 0;
  while (e >= a.n[i]) { e -= a.n[i]; ++i; }
  int srcb16 = flags[1];
  if (a.isb16[i]) {
    uint16_t v = srcb16 ? ((const uint16_t*)a.src[i])[e]
                        : f2b(((const float*)a.src[i])[e]);
    ((uint16_t*)a.dst[i])[e] = v;
  } else {
    float v = srcb16 ? bs2f(((const uint16_t*)a.src[i])[e])
                     : ((const float*)a.src[i])[e];
    ((float*)a.dst[i])[e] = v;
  }
}

// ---------- visible-index compaction (stable) ----------
__global__ __launch_bounds__(1024) void order_kernel(const void* mask,
                                                     const int* __restrict__ flags,
                                                     int* __restrict__ order) {
  int b = blockIdx.x, i = threadIdx.x;
  int f = flags[0];
  int mv;
  if (f == 0)      mv = (((const uint32_t*)mask)[b * N_TOK + i] != 0u);
  else if (f == 1) mv = (((const uint8_t*)mask)[b * N_TOK + i] != 0);
  else             mv = (((const uint16_t*)mask)[b * N_TOK + i] != 0);
  int vis = !mv;
  unsigned long long mb = __ballot(vis);
  int lane = i & 63, wid = i >> 6;
  int wpre = __popcll(mb & ((1ull << lane) - 1ull));
  __shared__ int wsum[16];
  __shared__ int woff[16];
  if (lane == 0) wsum[wid] = __popcll(mb);
  __syncthreads();
  if (i == 0) { int a = 0; for (int w = 0; w < 16; ++w) { woff[w] = a; a += wsum[w]; } }
  __syncthreads();
  if (vis) {
    int pos = woff[wid] + wpre;
    if (pos < LVIS) order[b * LVIS + pos] = i;
  }
}

// ---------- gather tokens -> residual (= r_1); rms -> rmsb16 ----------
__global__ __launch_bounds__(256) void gather_rms_kernel(const void* __restrict__ tokens,
                                                         const int* __restrict__ order,
                                                         const int* __restrict__ flags,
                                                         const float* __restrict__ nw,
                                                         float* __restrict__ residual,
                                                         uint16_t* __restrict__ rmsb16) {
  __shared__ float scr[4];
  int row = blockIdx.x;
  int b = row / LVIS;
  int d = threadIdx.x;
  int idx = order[row];
  size_t src = ((size_t)(b * N_TOK + idx)) * DM + d;
  float v = flags[1] ? bs2f(((const uint16_t*)tokens)[src]) : ((const float*)tokens)[src];
  size_t i = (size_t)row * DM + d;
  residual[i] = v;
  float ss = block_sum256(v * v, scr);
  rmsb16[i] = f2b(v * rsqrtf(ss / DM + EPS_F) * nw[d]);
}

// ---------- pipelined LDS-staged MFMA bf16 GEMM (in_proj), bf16 out ----------
#define GS 36
__global__ __launch_bounds__(256) void mfma_gemm_kernel(const uint16_t* __restrict__ A,
                                                        const uint16_t* __restrict__ W,
                                                        uint16_t* __restrict__ C,
                                                        int N, int K) {
  __shared__ uint16_t As[64 * GS];
  __shared__ uint16_t Ws[64 * GS];
  const int t = threadIdx.x;
  const int wv = t >> 6, lane = t & 63;
  const int lm = lane & 15, lq = lane >> 4;
  const int m0 = blockIdx.y * 64, n0 = blockIdx.x * 64;
  const int r = t >> 2, seg = t & 3;
  const uint16_t* ag = A + (size_t)(m0 + r) * K + seg * 8;
  const uint16_t* wg = W + (size_t)(n0 + r) * K + seg * 8;
  uint16_t* asl = As + r * GS + seg * 8;
  uint16_t* wsl = Ws + r * GS + seg * 8;
  const uint16_t* afr = As + (wv * 16 + lm) * GS + lq * 8;
  const uint16_t* wfr = Ws + lm * GS + lq * 8;
  f4v acc[4];
#pragma unroll
  for (int j = 0; j < 4; ++j) acc[j] = (f4v){0.f, 0.f, 0.f, 0.f};
  uint4 av = *(const uint4*)(ag);
  uint4 wvv = *(const uint4*)(wg);
  for (int k0 = 0; k0 < K; k0 += 32) {
    __syncthreads();
    *(uint4*)asl = av;
    *(uint4*)wsl = wvv;
    __syncthreads();
    if (k0 + 32 < K) {
      av = *(const uint4*)(ag + k0 + 32);
      wvv = *(const uint4*)(wg + k0 + 32);
    }
    s8v a = *(const s8v*)afr;
#pragma unroll
    for (int j = 0; j < 4; ++j) {
      s8v b = *(const s8v*)(wfr + j * 16 * GS);
      acc[j] = __builtin_amdgcn_mfma_f32_16x16x32_bf16(a, b, acc[j], 0, 0, 0);
    }
  }
#pragma unroll
  for (int j = 0; j < 4; ++j) {
    int col = n0 + j * 16 + lm;
#pragma unroll
    for (int rr = 0; rr < 4; ++rr) {
      int row = m0 + wv * 16 + lq * 4 + rr;
      C[(size_t)row * N + col] = f2b(acc[j][rr]);
    }
  }
}

// carry-state layout: idx(b,c,s,d) = ((b*NCHUNK + c)*16 + s)*DIN + d  (d innermost)
__device__ __forceinline__ size_t cidx(int b, int c, int s, int d) {
  return (((size_t)(b * NCHUNK + c) * 16 + s)) * DIN + d;
}

// ---------- scan1: fused conv+silu+x_proj GEMM (split-K-8, 8 waves) +
//            inline conv+dt + chunk-local scan. block = one (b,c), full d ----------
__global__ __launch_bounds__(512) void scan1_kernel(
    const uint16_t* __restrict__ xz16, const uint16_t* __restrict__ xw,
    const float* __restrict__ cw, const float* __restrict__ cb,
    const float* __restrict__ dtw, const float* __restrict__ dtb,
    const float* __restrict__ Alog,
    float* __restrict__ hend, float* __restrict__ pend,
    float* __restrict__ xdbl_out) {
  __shared__ float red[8][768];
  __shared__ float xds[CLEN * 48];
  const int t = threadIdx.x;
  const int c = blockIdx.x & (NCHUNK - 1);
  const int b = blockIdx.x >> 6;
  const int rowbase = b * LVIS + c * CLEN;
  // ---- GEMM phase: conv(4)+silu A-fragment, 16-row tile (12 used), K-slice 64/wave
  {
    const int wv = t >> 6, lane = t & 63;
    const int lm = lane & 15, lq = lane >> 4;
    int grow = rowbase + lm;
    if (grow > MROWS - 1) grow = MROWS - 1;  // pad-row clamp
    const int l = grow % LVIS;
    const uint16_t* xrow = xz16 + (size_t)grow * 1024;
    const bool t3 = l >= 3, t2 = l >= 2, t1 = l >= 1;
    const s8v zv = {0, 0, 0, 0, 0, 0, 0, 0};
    f4v acc[3];
#pragma unroll
    for (int j = 0; j < 3; ++j) acc[j] = (f4v){0.f, 0.f, 0.f, 0.f};
#pragma unroll
    for (int ki = 0; ki < 2; ++ki) {
      int kk = wv * 64 + ki * 32 + lq * 8;
      s8v x3 = t3 ? *(const s8v*)(xrow - 3 * 1024 + kk) : zv;
      s8v x2 = t2 ? *(const s8v*)(xrow - 2 * 1024 + kk) : zv;
      s8v x1 = t1 ? *(const s8v*)(xrow - 1 * 1024 + kk) : zv;
      s8v x0 = *(const s8v*)(xrow + kk);
      short av[8];
#pragma unroll
      for (int j = 0; j < 8; ++j) {
        int ch = kk + j;
        float4 w = *(const float4*)(cw + ch * 4);
        float a = cb[ch] + bs2f((uint16_t)x3[j]) * w.x + bs2f((uint16_t)x2[j]) * w.y +
                  bs2f((uint16_t)x1[j]) * w.z + bs2f((uint16_t)x0[j]) * w.w;
        av[j] = (short)f2b(silu_f(a));
      }
      s8v a8 = {av[0], av[1], av[2], av[3], av[4], av[5], av[6], av[7]};
#pragma unroll
      for (int j = 0; j < 3; ++j) {
        s8v bb = *(const s8v*)(xw + (size_t)(j * 16 + lm) * DIN + kk);
        acc[j] = __builtin_amdgcn_mfma_f32_16x16x32_bf16(a8, bb, acc[j], 0, 0, 0);
      }
    }
#pragma unroll
    for (int j = 0; j < 3; ++j)
#pragma unroll
      for (int rr = 0; rr < 4; ++rr)
        red[wv][(lq * 4 + rr) * 48 + j * 16 + lm] = acc[j][rr];
  }
  __syncthreads();
  for (int e = t; e < CLEN * 48; e += 512) {
    float v = red[0][e] + red[1][e] + red[2][e] + red[3][e] +
              red[4][e] + red[5][e] + red[6][e] + red[7][e];
    xds[e] = v;
    xdbl_out[(size_t)(rowbase + e / 48) * 48 + (e % 48)] = v;
  }
  // ---- scan phase ----
  const int d = t;
  float A[16], dw[16];
  {
    const float4* ap = (const float4*)(Alog + (size_t)d * 16);
    const float4* wp = (const float4*)(dtw + (size_t)d * 16);
#pragma unroll
    for (int q = 0; q < 4; ++q) {
      float4 a4 = ap[q], w4 = wp[q];
      A[4 * q + 0] = -__expf(a4.x); A[4 * q + 1] = -__expf(a4.y);
      A[4 * q + 2] = -__expf(a4.z); A[4 * q + 3] = -__expf(a4.w);
      dw[4 * q + 0] = w4.x; dw[4 * q + 1] = w4.y;
      dw[4 * q + 2] = w4.z; dw[4 * q + 3] = w4.w;
    }
  }
  float dtbv = dtb[d], cbv = cb[d];
  float4 cwv = *(const float4*)(cw + d * 4);
  float w3 = 0.f, w2 = 0.f, w1 = 0.f;
  if (c > 0) {
    w3 = bs2f(xz16[(size_t)(rowbase - 3) * 1024 + d]);
    w2 = bs2f(xz16[(size_t)(rowbase - 2) * 1024 + d]);
    w1 = bs2f(xz16[(size_t)(rowbase - 1) * 1024 + d]);
  }
  __syncthreads();
  float h[16], p[16];
#pragma unroll
  for (int s = 0; s < 16; ++s) { h[s] = 0.f; p[s] = 1.f; }
  for (int l = 0; l < CLEN; ++l) {
    int row = rowbase + l;
    float xn = bs2f(xz16[(size_t)row * 1024 + d]);
    float xv = silu_f(cbv + w3 * cwv.x + w2 * cwv.y + w1 * cwv.z + xn * cwv.w);
    w3 = w2; w2 = w1; w1 = xn;
    const float* xd = xds + l * 48;
    float dtraw = dtbv;
#pragma unroll
    for (int q = 0; q < 16; ++q) dtraw += xd[q] * dw[q];
    float dtv = softplus_f(dtraw);
    float dtx = dtv * xv;
#pragma unroll
    for (int s = 0; s < 16; ++s) {
      float dA = __expf(dtv * A[s]);
      h[s] = dA * h[s] + dtx * xd[16 + s];
      p[s] *= dA;
    }
  }
#pragma unroll
  for (int s = 0; s < 16; ++s) {
    hend[cidx(b, c, s, d)] = h[s];
    pend[cidx(b, c, s, d)] = p[s];
  }
}

// ---------- scan2: serial carry across chunks (coalesced, d innermost) ----------
__global__ __launch_bounds__(256) void scan2_kernel(const float* __restrict__ hend,
                                                    const float* __restrict__ pend,
                                                    float* __restrict__ hin) {
  int g = blockIdx.x * 256 + threadIdx.x;  // B_*16*DIN = 32768
  int d = g & (DIN - 1);
  int s = (g >> 9) & 15;
  int b = g >> 13;
  float h = 0.f;
  for (int c = 0; c < NCHUNK; ++c) {
    size_t idx = cidx(b, c, s, d);
    hin[idx] = h;
    h = pend[idx] * h + hend[idx];
  }
}

// ---------- scan3 + out_proj + residual + rms (fused) ----------
// block = one (b,c), 512 threads (8 waves). Scan writes ymul into LDS;
// GEMM: 16x256 tile (12 rows used), K=512 from LDS; epilogue does residual
// add + cross-wave rms + next-layer rmsb16.
__global__ __launch_bounds__(512) void scan3_fused_kernel(
    const uint16_t* __restrict__ xz16, const float* __restrict__ xdbl,
    const float* __restrict__ dtw, const float* __restrict__ dtb,
    const float* __restrict__ cw, const float* __restrict__ cb,
    const float* __restrict__ Alog, const float* __restrict__ Dskip,
    const float* __restrict__ hin, const uint16_t* __restrict__ W,
    const float* __restrict__ nw, float* __restrict__ residual,
    uint16_t* __restrict__ rmsb16) {
  __shared__ float xds[CLEN * 48];
  __shared__ uint16_t yml[16 * YS];
  __shared__ float part[16][8];
  __shared__ float scale[16];
  const int t = threadIdx.x;
  const int c = blockIdx.x & (NCHUNK - 1);
  const int b = blockIdx.x >> 6;
  const int rowbase = b * LVIS + c * CLEN;
  for (int e = t; e < CLEN * 48; e += 512)
    xds[e] = xdbl[(size_t)(rowbase + e / 48) * 48 + (e % 48)];
  // zero pad rows 12..15 of ymul tile
  for (int e = t; e < 4 * 512; e += 512)
    yml[(12 + (e >> 9)) * YS + (e & 511)] = 0;
  // ---- scan phase: d = t ----
  const int d = t;
  float A[16], dw[16];
  {
    const float4* ap = (const float4*)(Alog + (size_t)d * 16);
    const float4* wp = (const float4*)(dtw + (size_t)d * 16);
#pragma unroll
    for (int q = 0; q < 4; ++q) {
      float4 a4 = ap[q], w4 = wp[q];
      A[4 * q + 0] = -__expf(a4.x); A[4 * q + 1] = -__expf(a4.y);
      A[4 * q + 2] = -__expf(a4.z); A[4 * q + 3] = -__expf(a4.w);
      dw[4 * q + 0] = w4.x; dw[4 * q + 1] = w4.y;
      dw[4 * q + 2] = w4.z; dw[4 * q + 3] = w4.w;
    }
  }
  float h[16];
#pragma unroll
  for (int s = 0; s < 16; ++s) h[s] = hin[cidx(b, c, s, d)];
  float dtbv = dtb[d], cbv = cb[d], Dv = Dskip[d];
  float4 cwv = *(const float4*)(cw + d * 4);
  float w3 = 0.f, w2 = 0.f, w1 = 0.f;
  if (c > 0) {
    w3 = bs2f(xz16[(size_t)(rowbase - 3) * 1024 + d]);
    w2 = bs2f(xz16[(size_t)(rowbase - 2) * 1024 + d]);
    w1 = bs2f(xz16[(size_t)(rowbase - 1) * 1024 + d]);
  }
  __syncthreads();
  for (int l = 0; l < CLEN; ++l) {
    int row = rowbase + l;
    float xn = bs2f(xz16[(size_t)row * 1024 + d]);
    float xv = silu_f(cbv + w3 * cwv.x + w2 * cwv.y + w1 * cwv.z + xn * cwv.w);
    w3 = w2; w2 = w1; w1 = xn;
    const float* xd = xds + l * 48;
    float dtraw = dtbv;
#pragma unroll
    for (int q = 0; q < 16; ++q) dtraw += xd[q] * dw[q];
    float dtv = softplus_f(dtraw);
    float dtx = dtv * xv;
    float y = 0.f;
#pragma unroll
    for (int s = 0; s < 16; ++s) {
      float dA = __expf(dtv * A[s]);
      h[s] = dA * h[s] + dtx * xd[16 + s];
      y += h[s] * xd[32 + s];
    }
    float zv = bs2f(xz16[(size_t)row * 1024 + 512 + d]);
    yml[l * YS + d] = f2b((y + Dv * xv) * silu_f(zv));
  }
  __syncthreads();
  // ---- out_proj GEMM: wave wv handles n-tiles {2wv, 2wv+1} ----
  const int wv = t >> 6, lane = t & 63;
  const int lm = lane & 15, lq = lane >> 4;
  f4v acc[2];
  acc[0] = (f4v){0.f, 0.f, 0.f, 0.f};
  acc[1] = (f4v){0.f, 0.f, 0.f, 0.f};
  for (int k0 = 0; k0 < DIN; k0 += 32) {
    s8v a = *(const s8v*)(yml + lm * YS + k0 + lq * 8);
#pragma unroll
    for (int j = 0; j < 2; ++j) {
      int n = (2 * wv + j) * 16 + lm;
      s8v bf = *(const s8v*)(W + (size_t)n * DIN + k0 + lq * 8);
      acc[j] = __builtin_amdgcn_mfma_f32_16x16x32_bf16(a, bf, acc[j], 0, 0, 0);
    }
  }
  // ---- epilogue: residual add, cross-wave rms, write ----
  float vv[2][4];
  float sum[4] = {0.f, 0.f, 0.f, 0.f};
#pragma unroll
  for (int rr = 0; rr < 4; ++rr) {
    int row = lq * 4 + rr;
    if (row < CLEN) {
#pragma unroll
      for (int j = 0; j < 2; ++j) {
        int col = (2 * wv + j) * 16 + lm;
        float v = acc[j][rr] + residual[(size_t)(rowbase + row) * DM + col];
        vv[j][rr] = v;
        sum[rr] += v * v;
      }
    }
  }
#pragma unroll
  for (int rr = 0; rr < 4; ++rr) {
#pragma unroll
    for (int o = 1; o < 16; o <<= 1) sum[rr] += __shfl_xor(sum[rr], o);
  }
  if (lm == 0) {
#pragma unroll
    for (int rr = 0; rr < 4; ++rr) {
      int row = lq * 4 + rr;
      if (row < 16) part[row][wv] = sum[rr];
    }
  }
  __syncthreads();
  if (t < CLEN) {
    float s = 0.f;
#pragma unroll
    for (int w = 0; w < 8; ++w) s += part[t][w];
    scale[t] = rsqrtf(s / DM + EPS_F);
  }
  __syncthreads();
#pragma unroll
  for (int rr = 0; rr < 4; ++rr) {
    int row = lq * 4 + rr;
    if (row < CLEN) {
      float sc = scale[row];
#pragma unroll
      for (int j = 0; j < 2; ++j) {
        int col = (2 * wv + j) * 16 + lm;
        float v = vv[j][rr];
        size_t oi = (size_t)(rowbase + row) * DM + col;
        residual[oi] = v;
        rmsb16[oi] = f2b(v * sc * nw[col]);
      }
    }
  }
}

// ---------- final: rmsnorm(residual) -> layernorm -> out (flag-typed) ----------
__global__ __launch_bounds__(256) void final_kernel(const float* __restrict__ residual,
                                                    const float* __restrict__ nfw,
                                                    const float* __restrict__ lnw,
                                                    const float* __restrict__ lnb,
                                                    const int* __restrict__ flags,
                                                    void* __restrict__ out) {
  __shared__ float scr[4];
  int row = blockIdx.x, d = threadIdx.x;
  size_t i = (size_t)row * DM + d;
  float v = residual[i];
  float ss = block_sum256(v * v, scr);
  float h = v * rsqrtf(ss / DM + EPS_F) * nfw[d];
  float mu = block_sum256(h, scr) / DM;
  float dv = h - mu;
  float var = block_sum256(dv * dv, scr) / DM;
  float o = dv * rsqrtf(var + EPS_F) * lnw[d] + lnb[d];
  int b = row / LVIS, l = row % LVIS;
  size_t oi = (l < LVIS - 1)
                ? ((size_t)(b * (LVIS - 1) + l) * DM + d)
                : ((size_t)B_ * (LVIS - 1) * DM + (size_t)b * DM + d);
  if (flags[1]) ((uint16_t*)out)[oi] = f2b(o);
  else          ((float*)out)[oi] = o;
}

// ---------- host ----------
extern "C" void kernel_launch(void* const* d_in, const int* in_sizes, int n_in,
                              void* d_out, int out_size, void* d_ws, size_t ws_size,
                              hipStream_t stream) {
  char* ws = (char*)d_ws;
  size_t off = 0;
  auto alloc = [&](size_t bytes) -> void* {
    void* p = ws + off;
    off += (bytes + 255) & ~(size_t)255;
    return p;
  };
  const int f32_idx[10] = {3, 4, 6, 7, 8, 9, 11, 12, 13, 14};
  const int b16_idx[3]  = {2, 5, 10};
  float*    f32c[15] = {nullptr};
  uint16_t* b16c[15] = {nullptr};
  for (int j = 0; j < 10; ++j) {
    int i = f32_idx[j];
    f32c[i] = (float*)alloc((size_t)in_sizes[i] * 4);
  }
  for (int j = 0; j < 3; ++j) {
    int i = b16_idx[j];
    b16c[i] = (uint16_t*)alloc((size_t)in_sizes[i] * 2);
  }
  float*    residual = (float*)alloc((size_t)MROWS * DM * 4);
  uint16_t* rmsb16   = (uint16_t*)alloc((size_t)MROWS * DM * 2);
  uint16_t* xz16     = (uint16_t*)alloc((size_t)MROWS * 1024 * 2);
  float*    xdbl     = (float*)alloc((size_t)MROWS * 48 * 4);
  float*    hend     = (float*)alloc((size_t)B_ * NCHUNK * DIN * 16 * 4);
  float*    pend     = (float*)alloc((size_t)B_ * NCHUNK * DIN * 16 * 4);
  float*    hin      = (float*)alloc((size_t)B_ * NCHUNK * DIN * 16 * 4);
  int*      order    = (int*)alloc((size_t)B_ * LVIS * 4);
  int*      flags    = (int*)alloc(256);

  detect_kernel<<<1, 256, 0, stream>>>(d_in[1], (const uint32_t*)d_in[12], flags);

  CvtArgs ca;
  int total = 0, slot = 0;
  for (int j = 0; j < 3; ++j) {
    int i = b16_idx[j];
    ca.src[slot] = d_in[i]; ca.dst[slot] = b16c[i];
    ca.n[slot] = in_sizes[i]; ca.isb16[slot] = 1;
    total += in_sizes[i]; ++slot;
  }
  for (int j = 0; j < 10; ++j) {
    int i = f32_idx[j];
    ca.src[slot] = d_in[i]; ca.dst[slot] = f32c[i];
    ca.n[slot] = in_sizes[i]; ca.isb16[slot] = 0;
    total += in_sizes[i]; ++slot;
  }
  cvt_all_kernel<<<(total + 255) / 256, 256, 0, stream>>>(ca, total, flags);

  const uint16_t* in_w   = b16c[2];
  const float*    conv_w = f32c[3];
  const float*    conv_b = f32c[4];
  const uint16_t* x_w    = b16c[5];
  const float*    dt_w   = f32c[6];
  const float*    dt_b   = f32c[7];
  const float*    A_log  = f32c[8];
  const float*    D_skip = f32c[9];
  const uint16_t* out_w  = b16c[10];
  const float*    norm_w = f32c[11];
  const float*    norm_f = f32c[12];
  const float*    ln_w   = f32c[13];
  const float*    ln_b   = f32c[14];

  order_kernel<<<B_, 1024, 0, stream>>>(d_in[1], flags, order);
  gather_rms_kernel<<<MROWS, 256, 0, stream>>>(d_in[0], order, flags, norm_w,
                                               residual, rmsb16);

  for (int L = 0; L < DEPTH; ++L) {
    mfma_gemm_kernel<<<dim3(16, 48), 256, 0, stream>>>(
        rmsb16, in_w + (size_t)L * 1024 * DM, xz16, 1024, DM);
    scan1_kernel<<<B_ * NCHUNK, 512, 0, stream>>>(
        xz16, x_w + (size_t)L * 48 * DIN,
        conv_w + (size_t)L * DIN * 4, conv_b + (size_t)L * DIN,
        dt_w + (size_t)L * DIN * 16, dt_b + (size_t)L * DIN,
        A_log + (size_t)L * DIN * 16, hend, pend, xdbl);
    scan2_kernel<<<(B_ * 16 * DIN) / 256, 256, 0, stream>>>(hend, pend, hin);
    int Lnext = (L + 1 < DEPTH) ? (L + 1) : L;
    scan3_fused_kernel<<<B_ * NCHUNK, 512, 0, stream>>>(
        xz16, xdbl, dt_w + (size_t)L * DIN * 16, dt_b + (size_t)L * DIN,
        conv_w + (size_t)L * DIN * 4, conv_b + (size_t)L * DIN,
        A_log + (size_t)L * DIN * 16, D_skip + (size_t)L * DIN, hin,
        out_w + (size_t)L * DM * DIN, norm_w + (size_t)Lnext * DM,
        residual, rmsb16);
  }

  final_kernel<<<MROWS, 256, 0, stream>>>(residual, norm_f, ln_w, ln_b,
                                          flags, d_out);
}

// Round 13
// 996.229 us; speedup vs baseline: 1.4263x; 1.1015x over previous
//
#include <hip/hip_runtime.h>
#include <stdint.h>

#define B_ 4
#define N_TOK 1024
#define DM 256
#define DEPTH 12
#define DSTATE 16
#define DIN 512
#define LVIS 768
#define MROWS (B_ * LVIS)  // 3072
#define NCHUNK 64
#define CLEN 12            // 768 / 64
#define EPS_F 1e-5f
#define YS 520             // bf16 LDS row stride (shorts); 1040B, 16B-aligned
#define AS_ 264            // rms A-tile stride (shorts)

typedef __attribute__((ext_vector_type(8))) short s8v;   // 8 bf16 (4 VGPRs)
typedef __attribute__((ext_vector_type(4))) float f4v;   // 4 f32 acc

// ---------- helpers ----------
__device__ __forceinline__ float bs2f(uint32_t u) {
  uint32_t x = (u & 0xffffu) << 16;
  float f; __builtin_memcpy(&f, &x, 4); return f;
}
__device__ __forceinline__ uint16_t f2b(float f) {
  uint32_t u; __builtin_memcpy(&u, &f, 4);
  return (uint16_t)((u + 0x7fffu + ((u >> 16) & 1u)) >> 16);
}
__device__ __forceinline__ float silu_f(float x) { return x / (1.f + __expf(-x)); }
__device__ __forceinline__ float softplus_f(float x) {
  return fmaxf(x, 0.f) + log1pf(__expf(-fabsf(x)));
}
__device__ __forceinline__ float block_sum256(float v, volatile float* scr) {
  int t = threadIdx.x, lane = t & 63, wid = t >> 6;
#pragma unroll
  for (int o = 32; o > 0; o >>= 1) v += __shfl_down(v, o);
  __syncthreads();
  if (lane == 0) scr[wid] = v;
  __syncthreads();
  return scr[0] + scr[1] + scr[2] + scr[3];
}

// ---------- dtype detection ----------
__global__ void detect_kernel(const void* mask, const uint32_t* nf, int* flags) {
  __shared__ int cnt[3];
  int t = threadIdx.x;
  if (t < 3) cnt[t] = 0;
  __syncthreads();
  const uint32_t* pi = (const uint32_t*)mask;
  const uint16_t* ph = (const uint16_t*)mask;
  const uint8_t*  pb = (const uint8_t*)mask;
  int c32 = 0, cbf = 0, c8 = 0;
  for (int i = t; i < 1024; i += 256) {
    c32 += (pi[i] != 0u);
    cbf += (ph[i] != 0);
    c8  += (pb[i] != 0);
  }
  atomicAdd(&cnt[0], c32);
  atomicAdd(&cnt[1], cbf);
  atomicAdd(&cnt[2], c8);
  __syncthreads();
  if (t == 0) {
    int f;
    if (cnt[0] == 256) f = 0;
    else if (cnt[1] == 256) f = 2;
    else f = 1;
    flags[0] = f;
    flags[1] = (nf[0] == 0x3F800000u) ? 0 : 1;
  }
}

// ---------- single batched conversion of all 13 param arrays ----------
struct CvtArgs {
  const void* src[13];
  void*       dst[13];
  int         n[13];
  int         isb16[13];
};
__global__ __launch_bounds__(256) void cvt_all_kernel(CvtArgs a, int total,
                                                      const int* __restrict__ flags) {
  int e = blockIdx.x * 256 + threadIdx.x;
  if (e >= total) return;
  int i = 0;
  while (e >= a.n[i]) { e -= a.n[i]; ++i; }
  int srcb16 = flags[1];
  if (a.isb16[i]) {
    uint16_t v = srcb16 ? ((const uint16_t*)a.src[i])[e]
                        : f2b(((const float*)a.src[i])[e]);
    ((uint16_t*)a.dst[i])[e] = v;
  } else {
    float v = srcb16 ? bs2f(((const uint16_t*)a.src[i])[e])
                     : ((const float*)a.src[i])[e];
    ((float*)a.dst[i])[e] = v;
  }
}

// ---------- visible-index compaction (stable) ----------
__global__ __launch_bounds__(1024) void order_kernel(const void* mask,
                                                     const int* __restrict__ flags,
                                                     int* __restrict__ order) {
  int b = blockIdx.x, i = threadIdx.x;
  int f = flags[0];
  int mv;
  if (f == 0)      mv = (((const uint32_t*)mask)[b * N_TOK + i] != 0u);
  else if (f == 1) mv = (((const uint8_t*)mask)[b * N_TOK + i] != 0);
  else             mv = (((const uint16_t*)mask)[b * N_TOK + i] != 0);
  int vis = !mv;
  unsigned long long mb = __ballot(vis);
  int lane = i & 63, wid = i >> 6;
  int wpre = __popcll(mb & ((1ull << lane) - 1ull));
  __shared__ int wsum[16];
  __shared__ int woff[16];
  if (lane == 0) wsum[wid] = __popcll(mb);
  __syncthreads();
  if (i == 0) { int a = 0; for (int w = 0; w < 16; ++w) { woff[w] = a; a += wsum[w]; } }
  __syncthreads();
  if (vis) {
    int pos = woff[wid] + wpre;
    if (pos < LVIS) order[b * LVIS + pos] = i;
  }
}

// ---------- gather tokens -> residual (= r_1); rms -> rmsb16 ----------
__global__ __launch_bounds__(256) void gather_rms_kernel(const void* __restrict__ tokens,
                                                         const int* __restrict__ order,
                                                         const int* __restrict__ flags,
                                                         const float* __restrict__ nw,
                                                         float* __restrict__ residual,
                                                         uint16_t* __restrict__ rmsb16) {
  __shared__ float scr[4];
  int row = blockIdx.x;
  int b = row / LVIS;
  int d = threadIdx.x;
  int idx = order[row];
  size_t src = ((size_t)(b * N_TOK + idx)) * DM + d;
  float v = flags[1] ? bs2f(((const uint16_t*)tokens)[src]) : ((const float*)tokens)[src];
  size_t i = (size_t)row * DM + d;
  residual[i] = v;
  float ss = block_sum256(v * v, scr);
  rmsb16[i] = f2b(v * rsqrtf(ss / DM + EPS_F) * nw[d]);
}

// carry-state layout: idx(b,c,s,d) = ((b*NCHUNK + c)*16 + s)*DIN + d  (d innermost)
__device__ __forceinline__ size_t cidx(int b, int c, int s, int d) {
  return (((size_t)(b * NCHUNK + c) * 16 + s)) * DIN + d;
}

// ---------- scan1big: in_proj GEMM (16 rows incl. 3 lookback) + conv+silu +
//            x_proj GEMM (split-K-8) + dt + chunk-local scan.
// block = one (b,c), 512 threads (8 waves). grid = B_*NCHUNK = 256.
__global__ __launch_bounds__(512) void scan1_kernel(
    const uint16_t* __restrict__ rmsb16, const uint16_t* __restrict__ inw,
    const uint16_t* __restrict__ xw,
    const float* __restrict__ cw, const float* __restrict__ cb,
    const float* __restrict__ dtw, const float* __restrict__ dtb,
    const float* __restrict__ Alog,
    uint16_t* __restrict__ xz16, float* __restrict__ hend,
    float* __restrict__ pend, float* __restrict__ xdbl_out) {
  __shared__ uint16_t As[16 * AS_];   // rms input tile (16 x 256)
  __shared__ uint16_t xzl[16 * YS];   // x-half of in_proj output (16 x 512)
  __shared__ float red[8][768];
  __shared__ float xds[CLEN * 48];
  const int t = threadIdx.x;
  const int wv = t >> 6, lane = t & 63;
  const int lm = lane & 15, lq = lane >> 4;
  const int c = blockIdx.x & (NCHUNK - 1);
  const int b = blockIdx.x >> 6;
  const int rowbase = b * LVIS + c * CLEN;
  // ---- stage rms A-tile: tile row i <-> global row clamp(rowbase-3+i) ----
  {
    int r = t >> 5, seg = t & 31;
    int grow = rowbase - 3 + r;
    if (grow < 0) grow = 0;
    if (grow > MROWS - 1) grow = MROWS - 1;
    *(uint4*)(As + r * AS_ + seg * 8) =
        *(const uint4*)(rmsb16 + (size_t)grow * DM + seg * 8);
  }
  __syncthreads();
  // ---- in_proj GEMM: wave wv -> n-tiles 8wv..8wv+7 (cols 128wv..127) ----
  {
    f4v acc[8];
#pragma unroll
    for (int j = 0; j < 8; ++j) acc[j] = (f4v){0.f, 0.f, 0.f, 0.f};
    for (int k0 = 0; k0 < DM; k0 += 32) {
      s8v a = *(const s8v*)(As + lm * AS_ + k0 + lq * 8);
#pragma unroll
      for (int j = 0; j < 8; ++j) {
        int n = (8 * wv + j) * 16 + lm;
        s8v bw = *(const s8v*)(inw + (size_t)n * DM + k0 + lq * 8);
        acc[j] = __builtin_amdgcn_mfma_f32_16x16x32_bf16(a, bw, acc[j], 0, 0, 0);
      }
    }
#pragma unroll
    for (int j = 0; j < 8; ++j) {
      int col = (8 * wv + j) * 16 + lm;
#pragma unroll
      for (int rr = 0; rr < 4; ++rr) {
        int tr = lq * 4 + rr;            // tile row 0..15
        uint16_t v = f2b(acc[j][rr]);
        if (col < 512) xzl[tr * YS + col] = v;
        if (tr >= 3 && tr < 15)          // own rows rowbase..rowbase+11
          xz16[(size_t)(rowbase + tr - 3) * 1024 + col] = v;
      }
    }
  }
  __syncthreads();
  // ---- conv+silu + x_proj GEMM (split-K-8, K-slice 64/wave) ----
  {
    f4v acc[3];
#pragma unroll
    for (int j = 0; j < 3; ++j) acc[j] = (f4v){0.f, 0.f, 0.f, 0.f};
    const int l = c * CLEN + lm;         // position within batch row
    const bool t3 = l >= 3, t2 = l >= 2, t1 = l >= 1;
#pragma unroll
    for (int ki = 0; ki < 2; ++ki) {
      int kk = wv * 64 + ki * 32 + lq * 8;
      s8v a8 = {0, 0, 0, 0, 0, 0, 0, 0};
      if (lm < CLEN) {
        const s8v zv = {0, 0, 0, 0, 0, 0, 0, 0};
        s8v x0 = *(const s8v*)(xzl + (lm + 3) * YS + kk);
        s8v x1 = t1 ? *(const s8v*)(xzl + (lm + 2) * YS + kk) : zv;
        s8v x2 = t2 ? *(const s8v*)(xzl + (lm + 1) * YS + kk) : zv;
        s8v x3 = t3 ? *(const s8v*)(xzl + (lm + 0) * YS + kk) : zv;
#pragma unroll
        for (int j = 0; j < 8; ++j) {
          int ch = kk + j;
          float4 w = *(const float4*)(cw + ch * 4);
          float a = cb[ch] + bs2f((uint16_t)x3[j]) * w.x +
                    bs2f((uint16_t)x2[j]) * w.y +
                    bs2f((uint16_t)x1[j]) * w.z + bs2f((uint16_t)x0[j]) * w.w;
          a8[j] = (short)f2b(silu_f(a));
        }
      }
#pragma unroll
      for (int j = 0; j < 3; ++j) {
        s8v bb = *(const s8v*)(xw + (size_t)(j * 16 + lm) * DIN + kk);
        acc[j] = __builtin_amdgcn_mfma_f32_16x16x32_bf16(a8, bb, acc[j], 0, 0, 0);
      }
    }
#pragma unroll
    for (int j = 0; j < 3; ++j)
#pragma unroll
      for (int rr = 0; rr < 4; ++rr)
        red[wv][(lq * 4 + rr) * 48 + j * 16 + lm] = acc[j][rr];
  }
  __syncthreads();
  for (int e = t; e < CLEN * 48; e += 512) {
    float v = red[0][e] + red[1][e] + red[2][e] + red[3][e] +
              red[4][e] + red[5][e] + red[6][e] + red[7][e];
    xds[e] = v;
    xdbl_out[(size_t)(rowbase + e / 48) * 48 + (e % 48)] = v;
  }
  // ---- scan phase: d = t ----
  const int d = t;
  float A[16], dw[16];
  {
    const float4* ap = (const float4*)(Alog + (size_t)d * 16);
    const float4* wp = (const float4*)(dtw + (size_t)d * 16);
#pragma unroll
    for (int q = 0; q < 4; ++q) {
      float4 a4 = ap[q], w4 = wp[q];
      A[4 * q + 0] = -__expf(a4.x); A[4 * q + 1] = -__expf(a4.y);
      A[4 * q + 2] = -__expf(a4.z); A[4 * q + 3] = -__expf(a4.w);
      dw[4 * q + 0] = w4.x; dw[4 * q + 1] = w4.y;
      dw[4 * q + 2] = w4.z; dw[4 * q + 3] = w4.w;
    }
  }
  float dtbv = dtb[d], cbv = cb[d];
  float4 cwv = *(const float4*)(cw + d * 4);
  __syncthreads();
  float w3 = 0.f, w2 = 0.f, w1 = 0.f;
  if (c > 0) {
    w3 = bs2f(xzl[0 * YS + d]);
    w2 = bs2f(xzl[1 * YS + d]);
    w1 = bs2f(xzl[2 * YS + d]);
  }
  float h[16], p[16];
#pragma unroll
  for (int s = 0; s < 16; ++s) { h[s] = 0.f; p[s] = 1.f; }
  for (int l = 0; l < CLEN; ++l) {
    float xn = bs2f(xzl[(l + 3) * YS + d]);
    float xv = silu_f(cbv + w3 * cwv.x + w2 * cwv.y + w1 * cwv.z + xn * cwv.w);
    w3 = w2; w2 = w1; w1 = xn;
    const float* xd = xds + l * 48;
    float dtraw = dtbv;
#pragma unroll
    for (int q = 0; q < 16; ++q) dtraw += xd[q] * dw[q];
    float dtv = softplus_f(dtraw);
    float dtx = dtv * xv;
#pragma unroll
    for (int s = 0; s < 16; ++s) {
      float dA = __expf(dtv * A[s]);
      h[s] = dA * h[s] + dtx * xd[16 + s];
      p[s] *= dA;
    }
  }
#pragma unroll
  for (int s = 0; s < 16; ++s) {
    hend[cidx(b, c, s, d)] = h[s];
    pend[cidx(b, c, s, d)] = p[s];
  }
}

// ---------- scan2: serial carry across chunks (coalesced, d innermost) ----------
__global__ __launch_bounds__(256) void scan2_kernel(const float* __restrict__ hend,
                                                    const float* __restrict__ pend,
                                                    float* __restrict__ hin) {
  int g = blockIdx.x * 256 + threadIdx.x;  // B_*16*DIN = 32768
  int d = g & (DIN - 1);
  int s = (g >> 9) & 15;
  int b = g >> 13;
  float h = 0.f;
  for (int c = 0; c < NCHUNK; ++c) {
    size_t idx = cidx(b, c, s, d);
    hin[idx] = h;
    h = pend[idx] * h + hend[idx];
  }
}

// ---------- scan3 + out_proj + residual + rms (fused) ----------
__global__ __launch_bounds__(512) void scan3_fused_kernel(
    const uint16_t* __restrict__ xz16, const float* __restrict__ xdbl,
    const float* __restrict__ dtw, const float* __restrict__ dtb,
    const float* __restrict__ cw, const float* __restrict__ cb,
    const float* __restrict__ Alog, const float* __restrict__ Dskip,
    const float* __restrict__ hin, const uint16_t* __restrict__ W,
    const float* __restrict__ nw, float* __restrict__ residual,
    uint16_t* __restrict__ rmsb16) {
  __shared__ float xds[CLEN * 48];
  __shared__ uint16_t yml[16 * YS];
  __shared__ float part[16][8];
  __shared__ float scale[16];
  const int t = threadIdx.x;
  const int c = blockIdx.x & (NCHUNK - 1);
  const int b = blockIdx.x >> 6;
  const int rowbase = b * LVIS + c * CLEN;
  for (int e = t; e < CLEN * 48; e += 512)
    xds[e] = xdbl[(size_t)(rowbase + e / 48) * 48 + (e % 48)];
  for (int e = t; e < 4 * 512; e += 512)
    yml[(12 + (e >> 9)) * YS + (e & 511)] = 0;
  const int d = t;
  float A[16], dw[16];
  {
    const float4* ap = (const float4*)(Alog + (size_t)d * 16);
    const float4* wp = (const float4*)(dtw + (size_t)d * 16);
#pragma unroll
    for (int q = 0; q < 4; ++q) {
      float4 a4 = ap[q], w4 = wp[q];
      A[4 * q + 0] = -__expf(a4.x); A[4 * q + 1] = -__expf(a4.y);
      A[4 * q + 2] = -__expf(a4.z); A[4 * q + 3] = -__expf(a4.w);
      dw[4 * q + 0] = w4.x; dw[4 * q + 1] = w4.y;
      dw[4 * q + 2] = w4.z; dw[4 * q + 3] = w4.w;
    }
  }
  float h[16];
#pragma unroll
  for (int s = 0; s < 16; ++s) h[s] = hin[cidx(b, c, s, d)];
  float dtbv = dtb[d], cbv = cb[d], Dv = Dskip[d];
  float4 cwv = *(const float4*)(cw + d * 4);
  float w3 = 0.f, w2 = 0.f, w1 = 0.f;
  if (c > 0) {
    w3 = bs2f(xz16[(size_t)(rowbase - 3) * 1024 + d]);
    w2 = bs2f(xz16[(size_t)(rowbase - 2) * 1024 + d]);
    w1 = bs2f(xz16[(size_t)(rowbase - 1) * 1024 + d]);
  }
  __syncthreads();
  for (int l = 0; l < CLEN; ++l) {
    int row = rowbase + l;
    float xn = bs2f(xz16[(size_t)row * 1024 + d]);
    float xv = silu_f(cbv + w3 * cwv.x + w2 * cwv.y + w1 * cwv.z + xn * cwv.w);
    w3 = w2; w2 = w1; w1 = xn;
    const float* xd = xds + l * 48;
    float dtraw = dtbv;
#pragma unroll
    for (int q = 0; q < 16; ++q) dtraw += xd[q] * dw[q];
    float dtv = softplus_f(dtraw);
    float dtx = dtv * xv;
    float y = 0.f;
#pragma unroll
    for (int s = 0; s < 16; ++s) {
      float dA = __expf(dtv * A[s]);
      h[s] = dA * h[s] + dtx * xd[16 + s];
      y += h[s] * xd[32 + s];
    }
    float zv = bs2f(xz16[(size_t)row * 1024 + 512 + d]);
    yml[l * YS + d] = f2b((y + Dv * xv) * silu_f(zv));
  }
  __syncthreads();
  const int wv = t >> 6, lane = t & 63;
  const int lm = lane & 15, lq = lane >> 4;
  f4v acc[2];
  acc[0] = (f4v){0.f, 0.f, 0.f, 0.f};
  acc[1] = (f4v){0.f, 0.f, 0.f, 0.f};
  for (int k0 = 0; k0 < DIN; k0 += 32) {
    s8v a = *(const s8v*)(yml + lm * YS + k0 + lq * 8);
#pragma unroll
    for (int j = 0; j < 2; ++j) {
      int n = (2 * wv + j) * 16 + lm;
      s8v bf = *(const s8v*)(W + (size_t)n * DIN + k0 + lq * 8);
      acc[j] = __builtin_amdgcn_mfma_f32_16x16x32_bf16(a, bf, acc[j], 0, 0, 0);
    }
  }
  float vv[2][4];
  float sum[4] = {0.f, 0.f, 0.f, 0.f};
#pragma unroll
  for (int rr = 0; rr < 4; ++rr) {
    int row = lq * 4 + rr;
    if (row < CLEN) {
#pragma unroll
      for (int j = 0; j < 2; ++j) {
        int col = (2 * wv + j) * 16 + lm;
        float v = acc[j][rr] + residual[(size_t)(rowbase + row) * DM + col];
        vv[j][rr] = v;
        sum[rr] += v * v;
      }
    }
  }
#pragma unroll
  for (int rr = 0; rr < 4; ++rr) {
#pragma unroll
    for (int o = 1; o < 16; o <<= 1) sum[rr] += __shfl_xor(sum[rr], o);
  }
  if (lm == 0) {
#pragma unroll
    for (int rr = 0; rr < 4; ++rr) {
      int row = lq * 4 + rr;
      if (row < 16) part[row][wv] = sum[rr];
    }
  }
  __syncthreads();
  if (t < CLEN) {
    float s = 0.f;
#pragma unroll
    for (int w = 0; w < 8; ++w) s += part[t][w];
    scale[t] = rsqrtf(s / DM + EPS_F);
  }
  __syncthreads();
#pragma unroll
  for (int rr = 0; rr < 4; ++rr) {
    int row = lq * 4 + rr;
    if (row < CLEN) {
      float sc = scale[row];
#pragma unroll
      for (int j = 0; j < 2; ++j) {
        int col = (2 * wv + j) * 16 + lm;
        float v = vv[j][rr];
        size_t oi = (size_t)(rowbase + row) * DM + col;
        residual[oi] = v;
        rmsb16[oi] = f2b(v * sc * nw[col]);
      }
    }
  }
}

// ---------- final: rmsnorm(residual) -> layernorm -> out (flag-typed) ----------
__global__ __launch_bounds__(256) void final_kernel(const float* __restrict__ residual,
                                                    const float* __restrict__ nfw,
                                                    const float* __restrict__ lnw,
                                                    const float* __restrict__ lnb,
                                                    const int* __restrict__ flags,
                                                    void* __restrict__ out) {
  __shared__ float scr[4];
  int row = blockIdx.x, d = threadIdx.x;
  size_t i = (size_t)row * DM + d;
  float v = residual[i];
  float ss = block_sum256(v * v, scr);
  float h = v * rsqrtf(ss / DM + EPS_F) * nfw[d];
  float mu = block_sum256(h, scr) / DM;
  float dv = h - mu;
  float var = block_sum256(dv * dv, scr) / DM;
  float o = dv * rsqrtf(var + EPS_F) * lnw[d] + lnb[d];
  int b = row / LVIS, l = row % LVIS;
  size_t oi = (l < LVIS - 1)
                ? ((size_t)(b * (LVIS - 1) + l) * DM + d)
                : ((size_t)B_ * (LVIS - 1) * DM + (size_t)b * DM + d);
  if (flags[1]) ((uint16_t*)out)[oi] = f2b(o);
  else          ((float*)out)[oi] = o;
}

// ---------- host ----------
extern "C" void kernel_launch(void* const* d_in, const int* in_sizes, int n_in,
                              void* d_out, int out_size, void* d_ws, size_t ws_size,
                              hipStream_t stream) {
  char* ws = (char*)d_ws;
  size_t off = 0;
  auto alloc = [&](size_t bytes) -> void* {
    void* p = ws + off;
    off += (bytes + 255) & ~(size_t)255;
    return p;
  };
  const int f32_idx[10] = {3, 4, 6, 7, 8, 9, 11, 12, 13, 14};
  const int b16_idx[3]  = {2, 5, 10};
  float*    f32c[15] = {nullptr};
  uint16_t* b16c[15] = {nullptr};
  for (int j = 0; j < 10; ++j) {
    int i = f32_idx[j];
    f32c[i] = (float*)alloc((size_t)in_sizes[i] * 4);
  }
  for (int j = 0; j < 3; ++j) {
    int i = b16_idx[j];
    b16c[i] = (uint16_t*)alloc((size_t)in_sizes[i] * 2);
  }
  float*    residual = (float*)alloc((size_t)MROWS * DM * 4);
  uint16_t* rmsb16   = (uint16_t*)alloc((size_t)MROWS * DM * 2);
  uint16_t* xz16     = (uint16_t*)alloc((size_t)MROWS * 1024 * 2);
  float*    xdbl     = (float*)alloc((size_t)MROWS * 48 * 4);
  float*    hend     = (float*)alloc((size_t)B_ * NCHUNK * DIN * 16 * 4);
  float*    pend     = (float*)alloc((size_t)B_ * NCHUNK * DIN * 16 * 4);
  float*    hin      = (float*)alloc((size_t)B_ * NCHUNK * DIN * 16 * 4);
  int*      order    = (int*)alloc((size_t)B_ * LVIS * 4);
  int*      flags    = (int*)alloc(256);

  detect_kernel<<<1, 256, 0, stream>>>(d_in[1], (const uint32_t*)d_in[12], flags);

  CvtArgs ca;
  int total = 0, slot = 0;
  for (int j = 0; j < 3; ++j) {
    int i = b16_idx[j];
    ca.src[slot] = d_in[i]; ca.dst[slot] = b16c[i];
    ca.n[slot] = in_sizes[i]; ca.isb16[slot] = 1;
    total += in_sizes[i]; ++slot;
  }
  for (int j = 0; j < 10; ++j) {
    int i = f32_idx[j];
    ca.src[slot] = d_in[i]; ca.dst[slot] = f32c[i];
    ca.n[slot] = in_sizes[i]; ca.isb16[slot] = 0;
    total += in_sizes[i]; ++slot;
  }
  cvt_all_kernel<<<(total + 255) / 256, 256, 0, stream>>>(ca, total, flags);

  const uint16_t* in_w   = b16c[2];
  const float*    conv_w = f32c[3];
  const float*    conv_b = f32c[4];
  const uint16_t* x_w    = b16c[5];
  const float*    dt_w   = f32c[6];
  const float*    dt_b   = f32c[7];
  const float*    A_log  = f32c[8];
  const float*    D_skip = f32c[9];
  const uint16_t* out_w  = b16c[10];
  const float*    norm_w = f32c[11];
  const float*    norm_f = f32c[12];
  const float*    ln_w   = f32c[13];
  const float*    ln_b   = f32c[14];

  order_kernel<<<B_, 1024, 0, stream>>>(d_in[1], flags, order);
  gather_rms_kernel<<<MROWS, 256, 0, stream>>>(d_in[0], order, flags, norm_w,
                                               residual, rmsb16);

  for (int L = 0; L < DEPTH; ++L) {
    scan1_kernel<<<B_ * NCHUNK, 512, 0, stream>>>(
        rmsb16, in_w + (size_t)L * 1024 * DM, x_w + (size_t)L * 48 * DIN,
        conv_w + (size_t)L * DIN * 4, conv_b + (size_t)L * DIN,
        dt_w + (size_t)L * DIN * 16, dt_b + (size_t)L * DIN,
        A_log + (size_t)L * DIN * 16, xz16, hend, pend, xdbl);
    scan2_kernel<<<(B_ * 16 * DIN) / 256, 256, 0, stream>>>(hend, pend, hin);
    int Lnext = (L + 1 < DEPTH) ? (L + 1) : L;
    scan3_fused_kernel<<<B_ * NCHUNK, 512, 0, stream>>>(
        xz16, xdbl, dt_w + (size_t)L * DIN * 16, dt_b + (size_t)L * DIN,
        conv_w + (size_t)L * DIN * 4, conv_b + (size_t)L * DIN,
        A_log + (size_t)L * DIN * 16, D_skip + (size_t)L * DIN, hin,
        out_w + (size_t)L * DM * DIN, norm_w + (size_t)Lnext * DM,
        residual, rmsb16);
  }

  final_kernel<<<MROWS, 256, 0, stream>>>(residual, norm_f, ln_w, ln_b,
                                          flags, d_out);
}